// Round 8
// baseline (277.116 us; speedup 1.0000x reference)
//
#include <hip/hip_runtime.h>
#include <hip/hip_bf16.h>
#include <stdint.h>
#include <math.h>

#define SEQ 4096
#define DIM 1024
#define NHEADS 16
#define DHEAD 64
#define INNER 1024

typedef __hip_bfloat16 bf16;
typedef __attribute__((ext_vector_type(8))) short short8;
typedef __attribute__((ext_vector_type(4))) float floatx4;
typedef __attribute__((ext_vector_type(16))) float floatx16;

// async global->LDS, 16B per lane; lane i's 16B lands at dest + i*16.
__device__ __forceinline__ void gll16(const bf16* g, bf16* l) {
    __builtin_amdgcn_global_load_lds(
        (const __attribute__((address_space(1))) unsigned int*)g,
        (__attribute__((address_space(3))) unsigned int*)l,
        16, 0, 0);
}

__device__ __forceinline__ unsigned short f2bf_bits(float f) {
    bf16 h = __float2bfloat16(f);
    return *reinterpret_cast<unsigned short*>(&h);
}

__device__ __forceinline__ uint2 pack4bf(float a, float b, float c, float d) {
    __hip_bfloat162 lo = __float22bfloat162_rn(float2{a, b});
    __hip_bfloat162 hi = __float22bfloat162_rn(float2{c, d});
    uint2 r;
    r.x = *reinterpret_cast<unsigned*>(&lo);
    r.y = *reinterpret_cast<unsigned*>(&hi);
    return r;
}

// pack two f32 -> one dword of 2 bf16 (lo in [15:0], hi in [31:16]), RNE
__device__ __forceinline__ unsigned pkbf(float lo, float hi) {
    __hip_bfloat162 h = __float22bfloat162_rn(float2{lo, hi});
    return *reinterpret_cast<unsigned*>(&h);
}

// ---------------- prep: z=0..3 weight transpose+convert; z=4 x convert ----------------
__global__ __launch_bounds__(256) void prep_kernel(
        const float* __restrict__ x, const float* __restrict__ W0,
        const float* __restrict__ W1, const float* __restrict__ W2,
        const float* __restrict__ W3, bf16* __restrict__ xb,
        bf16* __restrict__ T0, bf16* __restrict__ T1,
        bf16* __restrict__ T2, bf16* __restrict__ T3) {
    const int tid = threadIdx.x + threadIdx.y * blockDim.x;  // 0..255
    if (blockIdx.z == 4) {
        // convert x: block (bx,by) -> chunk (by*32+bx) of 4096 floats
        int chunk = blockIdx.y * 32 + blockIdx.x;
        int base = chunk * 4096 + tid * 4;
        #pragma unroll
        for (int r = 0; r < 4; r++) {
            int i = base + r * 1024;
            float4 f = *reinterpret_cast<const float4*>(x + i);
            unsigned long long p = (unsigned long long)f2bf_bits(f.x)
                                 | ((unsigned long long)f2bf_bits(f.y) << 16)
                                 | ((unsigned long long)f2bf_bits(f.z) << 32)
                                 | ((unsigned long long)f2bf_bits(f.w) << 48);
            *reinterpret_cast<unsigned long long*>(xb + i) = p;
        }
        return;
    }
    const float* W; bf16* T;
    switch (blockIdx.z) {
        case 0:  W = W0; T = T0; break;
        case 1:  W = W1; T = T1; break;
        case 2:  W = W2; T = T2; break;
        default: W = W3; T = T3; break;
    }
    __shared__ float tile[32][33];
    int k0 = blockIdx.x * 32, n0 = blockIdx.y * 32;
    int tx = threadIdx.x, ty = threadIdx.y;
    #pragma unroll
    for (int i = 0; i < 4; i++)
        tile[ty + 8 * i][tx] = W[(size_t)(k0 + ty + 8 * i) * 1024 + n0 + tx];
    __syncthreads();
    #pragma unroll
    for (int i = 0; i < 4; i++)
        T[(size_t)(n0 + ty + 8 * i) * 1024 + k0 + tx] = __float2bfloat16(tile[tx][ty + 8 * i]);
}

// ---------------- 128x128 bf16 MFMA GEMM tile body, DIRECT global->reg ----------------
// R16 POST-MORTEM CHAIN: R14 (128², gll16+2-barrier) qkv=66 µs ~= 3 x out_gemm's
// 22 µs at 1 blk/CU -> co-resident blocks' K-loops SERIALIZE on the per-step
// vmcnt(0)+s_barrier drain. R15 (more blocks/CU) made it worse (77 µs, VALUBusy
// 7.5%) -> occupancy can't fill the drain. R16 removes the drain: this exact
// fragment layout is per-lane-contiguous 16B, so global_load_dwordx4 delivers
// the MFMA operand DIRECTLY (LDS staging only bought 2x fragment reuse; inputs
// are L2/LLC-resident so the extra reads are cheap). NO barriers, NO LDS, waves
// fully independent -> compiler pipelines loads across K-steps.
__device__ __forceinline__ void gemm128_direct(const bf16* __restrict__ A,
                                               const bf16* __restrict__ Bt,
                                               int m0, int n0, floatx4 acc[4][4]) {
    const int tid = threadIdx.x;
    const int wave = tid >> 6;
    const int lane = tid & 63;
    const int l15 = lane & 15;
    const int quad = lane >> 4;

    // per-lane fragment base: row = l15 (+16i), k = quad*8 (+32ks)
    const bf16* Ab = A + (size_t)(m0 + (wave >> 1) * 64 + l15) * 1024 + quad * 8;
    const bf16* Bb = Bt + (size_t)(n0 + (wave & 1) * 64 + l15) * 1024 + quad * 8;

    #pragma unroll
    for (int i = 0; i < 4; i++)
        #pragma unroll
        for (int j = 0; j < 4; j++)
            acc[i][j] = (floatx4){0.f, 0.f, 0.f, 0.f};

    for (int k0 = 0; k0 < 1024; k0 += 64) {
        short8 af[2][4], bfr[2][4];
        #pragma unroll
        for (int ks = 0; ks < 2; ks++)
            #pragma unroll
            for (int i = 0; i < 4; i++) {
                af[ks][i] = *reinterpret_cast<const short8*>(
                    Ab + (size_t)i * 16 * 1024 + k0 + ks * 32);
                bfr[ks][i] = *reinterpret_cast<const short8*>(
                    Bb + (size_t)i * 16 * 1024 + k0 + ks * 32);
            }
        #pragma unroll
        for (int ks = 0; ks < 2; ks++)
            #pragma unroll
            for (int i = 0; i < 4; i++)
                #pragma unroll
                for (int j = 0; j < 4; j++)
                    acc[i][j] = __builtin_amdgcn_mfma_f32_16x16x32_bf16(
                        af[ks][i], bfr[ks][j], acc[i][j], 0, 0, 0);
    }
}

// ---------------- QKV projection ----------------
// z=0: Q (scaled by beta*log2e so attention uses raw v_exp_f32; [h][seq][64])
// z=1: K ([h][seq][64])
// z=2: V written TRANSPOSED directly: Vt[h][d][seq] (b64 packed stores).
__global__ __launch_bounds__(256, 3) void qkv_gemm_kernel(
        const bf16* __restrict__ xb,
        const bf16* __restrict__ Wqt, const bf16* __restrict__ Wkt, const bf16* __restrict__ Wvt,
        bf16* __restrict__ Qh, bf16* __restrict__ Kh, bf16* __restrict__ Vt) {
    const bf16* Bt;
    if (blockIdx.z == 0)      Bt = Wqt;
    else if (blockIdx.z == 1) Bt = Wkt;
    else                      Bt = Wvt;
    int n0 = blockIdx.x * 128, m0 = blockIdx.y * 128;
    floatx4 acc[4][4];
    gemm128_direct(xb, Bt, m0, n0, acc);

    const int tid = threadIdx.x, wave = tid >> 6, lane = tid & 63;
    const int l15 = lane & 15, quad = lane >> 4;
    const int wm = (wave >> 1) * 64, wn = (wave & 1) * 64;
    if (blockIdx.z == 2) {
        #pragma unroll
        for (int i = 0; i < 4; i++)
            #pragma unroll
            for (int j = 0; j < 4; j++) {
                int col = n0 + wn + j * 16 + l15;
                int h = col >> 6, d = col & 63;
                int row0 = m0 + wm + i * 16 + quad * 4;
                uint2 v = pack4bf(acc[i][j][0], acc[i][j][1], acc[i][j][2], acc[i][j][3]);
                *reinterpret_cast<uint2*>(Vt + ((size_t)h * DHEAD + d) * SEQ + row0) = v;
            }
    } else {
        bf16* O = (blockIdx.z == 0) ? Qh : Kh;
        float scale = (blockIdx.z == 0) ? 0.125f * 1.4426950408889634f : 1.0f;
        #pragma unroll
        for (int i = 0; i < 4; i++)
            #pragma unroll
            for (int j = 0; j < 4; j++) {
                int col = n0 + wn + j * 16 + l15;
                int h = col >> 6, d = col & 63;
                #pragma unroll
                for (int r = 0; r < 4; r++) {
                    int row = m0 + wm + i * 16 + quad * 4 + r;
                    O[((size_t)h * SEQ + row) * DHEAD + d] = __float2bfloat16(acc[i][j][r] * scale);
                }
            }
    }
}

// ---------------- output projection: out = Oa @ Wo + bo (fp32 out) ----------------
__global__ __launch_bounds__(256, 3) void out_gemm_kernel(
        const bf16* __restrict__ Oa, const bf16* __restrict__ Wot,
        const float* __restrict__ bo, float* __restrict__ out) {
    int n0 = blockIdx.x * 128, m0 = blockIdx.y * 128;
    floatx4 acc[4][4];
    gemm128_direct(Oa, Wot, m0, n0, acc);

    const int tid = threadIdx.x, wave = tid >> 6, lane = tid & 63;
    const int l15 = lane & 15, quad = lane >> 4;
    const int wm = (wave >> 1) * 64, wn = (wave & 1) * 64;
    #pragma unroll
    for (int i = 0; i < 4; i++)
        #pragma unroll
        for (int j = 0; j < 4; j++) {
            int col = n0 + wn + j * 16 + l15;
            float b = bo[col];
            #pragma unroll
            for (int r = 0; r < 4; r++) {
                int row = m0 + wm + i * 16 + quad * 4 + r;
                out[(size_t)row * DIM + col] = acc[i][j][r] + b;
            }
        }
}

// ---------------- causal flash attention (R14: balanced trios over R13 core — WINNER, unchanged) ----------------
// R14 PM: balanced trio map (each CU trio sums 66 tile-units) -> attention left
// the top-5 (<66 µs, was 76.5). Core: mfma_f32_32x32x16_bf16, 4 waves x 32 q,
// BK=64 dbuf, 1 barrier/tile, LDS 32 KB, in-register P via cvt_pk +
// v_permlane32_swap_b32 (T12), split-key additive partials + combine.
// p = v_exp_f32(s) via __builtin_amdgcn_exp2f — do NOT use exp2f (libcall,
// +15 µs R8). DO NOT: drop staging (R6), occupancy <4 blk/CU (R10),
// per-wave K/V-quarter split (R12), unbalanced piece maps (R13).
#define PV_STEP(P, KTG)                                                              \
    do {                                                                             \
        const int rb_ = ((KTG) & 1) * 8;                                             \
        unsigned A0_ = pkbf((P)[rb_ + 0], (P)[rb_ + 1]);                             \
        unsigned B0_ = pkbf((P)[rb_ + 4], (P)[rb_ + 5]);                             \
        unsigned A1_ = pkbf((P)[rb_ + 2], (P)[rb_ + 3]);                             \
        unsigned B1_ = pkbf((P)[rb_ + 6], (P)[rb_ + 7]);                             \
        asm("v_permlane32_swap_b32 %0, %1" : "+v"(A0_), "+v"(B0_));                  \
        asm("v_permlane32_swap_b32 %0, %1" : "+v"(A1_), "+v"(B1_));                  \
        uint4 w_; w_.x = A0_; w_.y = A1_; w_.z = B0_; w_.w = B1_;                    \
        short8 bp_ = *reinterpret_cast<short8*>(&w_);                                \
        short8 av0_ = *reinterpret_cast<const short8*>(                              \
            &Vsh[cur][(KTG) * 512 + lane * 8]);                                      \
        short8 av1_ = *reinterpret_cast<const short8*>(                              \
            &Vsh[cur][(4 + (KTG)) * 512 + lane * 8]);                                \
        acc0 = __builtin_amdgcn_mfma_f32_32x32x16_bf16(av0_, bp_, acc0, 0, 0, 0);    \
        acc1 = __builtin_amdgcn_mfma_f32_32x32x16_bf16(av1_, bp_, acc1, 0, 0, 0);    \
    } while (0)

__global__ __launch_bounds__(256, 4) void attention_kernel(
        const bf16* __restrict__ Qh, const bf16* __restrict__ Kh,
        const bf16* __restrict__ Vt, bf16* __restrict__ Oa,
        float* __restrict__ Op0, float* __restrict__ Op1,
        float* __restrict__ L0, float* __restrict__ L1) {
    __shared__ __align__(16) bf16 Ksh[2][4096];  // 8 KB/buf: chunk t=g*4+kc (keys g*32.., k kc*16..)
    __shared__ __align__(16) bf16 Vsh[2][4096];  // 8 KB/buf: chunk t=dg*4+kt (d dg*32.., key kt*16..)
    const int tid = threadIdx.x, wave = tid >> 6, lane = tid & 63;
    const int ql = lane & 31, half = lane >> 5;
    const int h8 = half * 8;
    const int id = blockIdx.x;
    const int head = id & 15;                    // XCD id&7 serves heads {h, h+8}
    const int rk = id >> 4;                      // 0..47
    // BALANCED piece map: co-resident trio rk {r, r+16, r+32} sums to 66:
    // rk<16:      chunk0 of t=16+rk          (len 32)
    // rk in 16..31: chunk1 of t=47-rk        (len 32-2(rk-16))
    // rk in 32..47: single  t=rk-32          (len 2(rk-32)+2)
    int t, ck;
    if (rk < 16)      { t = 16 + rk; ck = 0; }
    else if (rk < 32) { t = 47 - rk; ck = 1; }
    else              { t = rk - 32; ck = 0; }
    const bool split = (t >= 16);
    const int ktile0 = (split && ck == 1) ? 32 : 0;
    const int ktile1 = (split && ck == 0) ? 32 : (2 * t + 2);
    const int qw = t * 128 + wave * 32;          // wave's 32 q-rows
    const int q = qw + ql;                       // this lane's q-row (n = lane&31)
    const size_t hoff = (size_t)head * SEQ * DHEAD;
    const bf16* Qb = Qh + hoff;
    const bf16* Kb = Kh + hoff;
    const bf16* Vb = Vt + hoff;                  // [d][seq]

    // Q as B-frags for 32x32x16: lane n=q, k = kc*16 + 8*half + j
    short8 bq[4];
    #pragma unroll
    for (int kc = 0; kc < 4; kc++)
        bq[kc] = *reinterpret_cast<const short8*>(
            Qb + (size_t)q * DHEAD + kc * 16 + h8);

    floatx16 acc0, acc1;                         // O: d = (reg&3)+8*(reg>>2)+4*half (+32 for acc1), col q
    #pragma unroll
    for (int r = 0; r < 16; r++) { acc0[r] = 0.f; acc1[r] = 0.f; }
    float l_part = 0.f;

    // per-wave stage of one 64-key K tile + V tile into buffer `buf`
    auto stage = [&](int buf, int kbase) {
        #pragma unroll
        for (int j = 0; j < 2; j++) {
            int tc = wave * 2 + j;               // 0..7 across 4 waves
            gll16(Kb + (size_t)(kbase + (tc >> 2) * 32 + ql) * DHEAD + (tc & 3) * 16 + h8,
                  &Ksh[buf][tc * 512]);
            gll16(Vb + (size_t)((tc >> 2) * 32 + ql) * SEQ + kbase + (tc & 3) * 16 + h8,
                  &Vsh[buf][tc * 512]);
        }
    };

    stage(0, ktile0 * 64);
    __syncthreads();                             // vmcnt(0) drain + first tile visible
    int cur = 0;
    for (int kt = ktile0; kt < ktile1; kt++) {
        const int kbase = kt * 64;
        if (kt + 1 < ktile1) stage(cur ^ 1, (kt + 1) * 64);  // async prefetch

        // S^T = K·Q^T: 8 A-frag reads feed 8 32x32x16 MFMAs (2 key-groups)
        floatx16 s0, s1;
        #pragma unroll
        for (int r = 0; r < 16; r++) { s0[r] = 0.f; s1[r] = 0.f; }
        __builtin_amdgcn_s_setprio(1);
        #pragma unroll
        for (int kc = 0; kc < 4; kc++) {
            short8 ak0 = *reinterpret_cast<const short8*>(&Ksh[cur][kc * 512 + lane * 8]);
            short8 ak1 = *reinterpret_cast<const short8*>(&Ksh[cur][(4 + kc) * 512 + lane * 8]);
            s0 = __builtin_amdgcn_mfma_f32_32x32x16_bf16(ak0, bq[kc], s0, 0, 0, 0);
            s1 = __builtin_amdgcn_mfma_f32_32x32x16_bf16(ak1, bq[kc], s1, 0, 0, 0);
        }
        __builtin_amdgcn_s_setprio(0);
        // causal mask: key = kbase + 32*sg + (r&3)+8*(r>>2)+4*half, q = q
        if (kbase + 63 > qw) {                   // wave-uniform
            int base0 = kbase + half * 4 - q;
            #pragma unroll
            for (int r = 0; r < 16; r++) {
                int off = (r & 3) + 8 * (r >> 2);
                if (base0 + off > 0)      s0[r] = -1e30f;
                if (base0 + 32 + off > 0) s1[r] = -1e30f;
            }
        }
        // p = 2^s in place (masked -> 0); per-lane denom partial
        #pragma unroll
        for (int r = 0; r < 16; r++) {
            s0[r] = __builtin_amdgcn_exp2f(s0[r]);
            s1[r] = __builtin_amdgcn_exp2f(s1[r]);
            l_part += s0[r] + s1[r];
        }
        // O += V^T·P: per 16-key slot build bp in-register (T12) + 2 MFMAs
        __builtin_amdgcn_s_setprio(1);
        PV_STEP(s0, 0); PV_STEP(s0, 1); PV_STEP(s1, 2); PV_STEP(s1, 3);
        __builtin_amdgcn_s_setprio(0);

        __syncthreads();                         // readers done + prefetch drained
        cur ^= 1;
    }
    // denom: lane holds half the keys; other half sits at lane^32
    float l = l_part + __shfl_xor(l_part, 32, 64);
    if (!split) {
        // single-chunk: finalize. Oa row-major [SEQ][INNER].
        float rcp = 1.0f / l;
        #pragma unroll
        for (int a = 0; a < 4; a++) {
            int d0 = 8 * a + half * 4;
            uint2 v0 = pack4bf(acc0[4 * a + 0] * rcp, acc0[4 * a + 1] * rcp,
                               acc0[4 * a + 2] * rcp, acc0[4 * a + 3] * rcp);
            *reinterpret_cast<uint2*>(Oa + (size_t)q * INNER + head * DHEAD + d0) = v0;
            uint2 v1 = pack4bf(acc1[4 * a + 0] * rcp, acc1[4 * a + 1] * rcp,
                               acc1[4 * a + 2] * rcp, acc1[4 * a + 3] * rcp);
            *reinterpret_cast<uint2*>(Oa + (size_t)q * INNER + head * DHEAD + 32 + d0) = v1;
        }
    } else {
        // split: write unnormalized fp32 partials (q in [2048,4096))
        float* Op = ck ? Op1 : Op0;
        float* Lp = ck ? L1 : L0;
        if (half == 0) Lp[head * 2048 + (q - 2048)] = l;
        #pragma unroll
        for (int a = 0; a < 4; a++) {
            int d0 = 8 * a + half * 4;
            floatx4 v0 = {acc0[4 * a + 0], acc0[4 * a + 1], acc0[4 * a + 2], acc0[4 * a + 3]};
            *reinterpret_cast<floatx4*>(
                Op + (size_t)(q - 2048) * INNER + head * DHEAD + d0) = v0;
            floatx4 v1 = {acc1[4 * a + 0], acc1[4 * a + 1], acc1[4 * a + 2], acc1[4 * a + 3]};
            *reinterpret_cast<floatx4*>(
                Op + (size_t)(q - 2048) * INNER + head * DHEAD + 32 + d0) = v1;
        }
    }
}

// ---------------- combine: rows 2048..4095 = (O0+O1)/(l0+l1) -> bf16 Oa ----------------
__global__ __launch_bounds__(256) void combine_kernel(
        const float* __restrict__ Op0, const float* __restrict__ Op1,
        const float* __restrict__ L0, const float* __restrict__ L1,
        bf16* __restrict__ Oa) {
    int idx = blockIdx.x * 256 + threadIdx.x;    // 524288 threads, 4 floats each
    int row = idx >> 8;                          // 0..2047 (q = 2048 + row)
    int c4 = (idx & 255) * 4;                    // col base
    int head = c4 >> 6;
    float l = L0[head * 2048 + row] + L1[head * 2048 + row];
    float rcp = 1.0f / l;
    float4 a = *reinterpret_cast<const float4*>(Op0 + (size_t)row * INNER + c4);
    float4 b = *reinterpret_cast<const float4*>(Op1 + (size_t)row * INNER + c4);
    uint2 v = pack4bf((a.x + b.x) * rcp, (a.y + b.y) * rcp,
                      (a.z + b.z) * rcp, (a.w + b.w) * rcp);
    *reinterpret_cast<uint2*>(Oa + (size_t)(2048 + row) * INNER + c4) = v;
}

extern "C" void kernel_launch(void* const* d_in, const int* in_sizes, int n_in,
                              void* d_out, int out_size, void* d_ws, size_t ws_size,
                              hipStream_t stream) {
    const float* x  = (const float*)d_in[0];
    const float* Wq = (const float*)d_in[1];
    const float* Wk = (const float*)d_in[2];
    const float* Wv = (const float*)d_in[3];
    const float* Wo = (const float*)d_in[4];
    const float* bo = (const float*)d_in[5];
    float* out = (float*)d_out;

    char* ws = (char*)d_ws;
    size_t off = 0;
    bf16* xb  = (bf16*)(ws + off); off += (size_t)SEQ * DIM * 2;
    bf16* Wqt = (bf16*)(ws + off); off += (size_t)DIM * INNER * 2;
    bf16* Wkt = (bf16*)(ws + off); off += (size_t)DIM * INNER * 2;
    bf16* Wvt = (bf16*)(ws + off); off += (size_t)DIM * INNER * 2;
    bf16* Wot = (bf16*)(ws + off); off += (size_t)INNER * DIM * 2;
    bf16* Qh  = (bf16*)(ws + off); off += (size_t)NHEADS * SEQ * DHEAD * 2;
    bf16* Kh  = (bf16*)(ws + off); off += (size_t)NHEADS * SEQ * DHEAD * 2;
    bf16* Vtr = (bf16*)(ws + off); off += (size_t)NHEADS * DHEAD * SEQ * 2;
    bf16* Oa  = (bf16*)(ws + off); off += (size_t)SEQ * INNER * 2;
    float* Op0 = (float*)(ws + off); off += (size_t)(SEQ / 2) * INNER * 4;  // 8 MB
    float* Op1 = (float*)(ws + off); off += (size_t)(SEQ / 2) * INNER * 4;  // 8 MB
    float* L0  = (float*)(ws + off); off += (size_t)NHEADS * (SEQ / 2) * 4;
    float* L1  = (float*)(ws + off); off += (size_t)NHEADS * (SEQ / 2) * 4;  // ~64.5 MB total

    prep_kernel<<<dim3(32, 32, 5), dim3(32, 8), 0, stream>>>(x, Wq, Wk, Wv, Wo,
                                                             xb, Wqt, Wkt, Wvt, Wot);
    qkv_gemm_kernel<<<dim3(8, 32, 3), 256, 0, stream>>>(xb, Wqt, Wkt, Wvt, Qh, Kh, Vtr);
    attention_kernel<<<768, 256, 0, stream>>>(Qh, Kh, Vtr, Oa, Op0, Op1, L0, L1);
    combine_kernel<<<2048, 256, 0, stream>>>(Op0, Op1, L0, L1, Oa);
    out_gemm_kernel<<<dim3(8, 32), 256, 0, stream>>>(Oa, Wot, bo, out);
}

// Round 9
// 236.861 us; speedup vs baseline: 1.1700x; 1.1700x over previous
//
#include <hip/hip_runtime.h>
#include <hip/hip_bf16.h>
#include <stdint.h>
#include <math.h>

#define SEQ 4096
#define DIM 1024
#define NHEADS 16
#define DHEAD 64
#define INNER 1024

typedef __hip_bfloat16 bf16;
typedef __attribute__((ext_vector_type(8))) short short8;
typedef __attribute__((ext_vector_type(4))) float floatx4;
typedef __attribute__((ext_vector_type(16))) float floatx16;

// async global->LDS, 16B per lane; lane i's 16B lands at dest + i*16.
__device__ __forceinline__ void gll16(const bf16* g, bf16* l) {
    __builtin_amdgcn_global_load_lds(
        (const __attribute__((address_space(1))) unsigned int*)g,
        (__attribute__((address_space(3))) unsigned int*)l,
        16, 0, 0);
}

__device__ __forceinline__ unsigned short f2bf_bits(float f) {
    bf16 h = __float2bfloat16(f);
    return *reinterpret_cast<unsigned short*>(&h);
}

__device__ __forceinline__ uint2 pack4bf(float a, float b, float c, float d) {
    __hip_bfloat162 lo = __float22bfloat162_rn(float2{a, b});
    __hip_bfloat162 hi = __float22bfloat162_rn(float2{c, d});
    uint2 r;
    r.x = *reinterpret_cast<unsigned*>(&lo);
    r.y = *reinterpret_cast<unsigned*>(&hi);
    return r;
}

// pack two f32 -> one dword of 2 bf16 (lo in [15:0], hi in [31:16]), RNE
__device__ __forceinline__ unsigned pkbf(float lo, float hi) {
    __hip_bfloat162 h = __float22bfloat162_rn(float2{lo, hi});
    return *reinterpret_cast<unsigned*>(&h);
}

// ---------------- prep: z=0..3 weight transpose+convert; z=4 x convert ----------------
__global__ __launch_bounds__(256) void prep_kernel(
        const float* __restrict__ x, const float* __restrict__ W0,
        const float* __restrict__ W1, const float* __restrict__ W2,
        const float* __restrict__ W3, bf16* __restrict__ xb,
        bf16* __restrict__ T0, bf16* __restrict__ T1,
        bf16* __restrict__ T2, bf16* __restrict__ T3) {
    const int tid = threadIdx.x + threadIdx.y * blockDim.x;  // 0..255
    if (blockIdx.z == 4) {
        // convert x: block (bx,by) -> chunk (by*32+bx) of 4096 floats
        int chunk = blockIdx.y * 32 + blockIdx.x;
        int base = chunk * 4096 + tid * 4;
        #pragma unroll
        for (int r = 0; r < 4; r++) {
            int i = base + r * 1024;
            float4 f = *reinterpret_cast<const float4*>(x + i);
            unsigned long long p = (unsigned long long)f2bf_bits(f.x)
                                 | ((unsigned long long)f2bf_bits(f.y) << 16)
                                 | ((unsigned long long)f2bf_bits(f.z) << 32)
                                 | ((unsigned long long)f2bf_bits(f.w) << 48);
            *reinterpret_cast<unsigned long long*>(xb + i) = p;
        }
        return;
    }
    const float* W; bf16* T;
    switch (blockIdx.z) {
        case 0:  W = W0; T = T0; break;
        case 1:  W = W1; T = T1; break;
        case 2:  W = W2; T = T2; break;
        default: W = W3; T = T3; break;
    }
    __shared__ float tile[32][33];
    int k0 = blockIdx.x * 32, n0 = blockIdx.y * 32;
    int tx = threadIdx.x, ty = threadIdx.y;
    #pragma unroll
    for (int i = 0; i < 4; i++)
        tile[ty + 8 * i][tx] = W[(size_t)(k0 + ty + 8 * i) * 1024 + n0 + tx];
    __syncthreads();
    #pragma unroll
    for (int i = 0; i < 4; i++)
        T[(size_t)(n0 + ty + 8 * i) * 1024 + k0 + tx] = __float2bfloat16(tile[tx][ty + 8 * i]);
}

// ---------------- 128x128 bf16 MFMA GEMM tile body, 2-PHASE DOUBLE-BUFFERED ----------------
// R17 POST-MORTEM CHAIN: R14 (single-buf, 2 barriers: barrier->stage->
// barrier(vmcnt0)->compute) = 66 µs qkv: the drain sits IMMEDIATELY after the
// load issue -> full L2 latency exposed x16 steps. R15 (more blocks) didn't
// fill it (77 µs); R16 (no LDS, direct reg) exposed per-load latency instead
// (98 µs, VGPR=56 serial chain). R17 = T3-minimum: stage tile k+1 into buf^1,
// THEN compute tile k (ds_read+32 MFMA hides the load latency), THEN one
// barrier (its vmcnt(0) lands after latency is covered). Same fragment
// layout/stage as R14 (proven); LDS 64 KB -> 2 blocks/CU.
__device__ __forceinline__ void gemm128_dbuf(const bf16* __restrict__ A,
                                             const bf16* __restrict__ Bt,
                                             int m0, int n0, floatx4 acc[4][4]) {
    __shared__ __align__(16) bf16 As[2][8192];
    __shared__ __align__(16) bf16 Bs[2][8192];
    const int tid = threadIdx.x;
    const int wave = tid >> 6;
    const int lane = tid & 63;
    const int l15 = lane & 15;
    const int quad = lane >> 4;

    #pragma unroll
    for (int i = 0; i < 4; i++)
        #pragma unroll
        for (int j = 0; j < 4; j++)
            acc[i][j] = (floatx4){0.f, 0.f, 0.f, 0.f};

    auto stage = [&](int buf, int k0) {
        #pragma unroll
        for (int j = 0; j < 4; j++) {
            int t = wave * 4 + j;
            int row = (t >> 1) * 16 + l15;
            int kb = (t & 1) * 32 + quad * 8;
            gll16(A + (size_t)(m0 + row) * 1024 + k0 + kb, &As[buf][t * 512]);
            gll16(Bt + (size_t)(n0 + row) * 1024 + k0 + kb, &Bs[buf][t * 512]);
        }
    };

    stage(0, 0);
    __syncthreads();                              // vmcnt(0) drain; tile 0 visible
    int cur = 0;
    for (int k0 = 0; k0 < 1024; k0 += 64) {
        if (k0 + 64 < 1024) stage(cur ^ 1, k0 + 64);   // async prefetch next tile
        #pragma unroll
        for (int ks = 0; ks < 2; ks++) {
            short8 af[4], bfr[4];
            #pragma unroll
            for (int i = 0; i < 4; i++)
                af[i] = *reinterpret_cast<const short8*>(
                    &As[cur][((((wave >> 1) * 4 + i) * 2 + ks) * 512) + lane * 8]);
            #pragma unroll
            for (int j = 0; j < 4; j++)
                bfr[j] = *reinterpret_cast<const short8*>(
                    &Bs[cur][((((wave & 1) * 4 + j) * 2 + ks) * 512) + lane * 8]);
            #pragma unroll
            for (int i = 0; i < 4; i++)
                #pragma unroll
                for (int j = 0; j < 4; j++)
                    acc[i][j] = __builtin_amdgcn_mfma_f32_16x16x32_bf16(af[i], bfr[j], acc[i][j], 0, 0, 0);
        }
        __syncthreads();                          // readers done + prefetch drained
        cur ^= 1;
    }
}

// ---------------- QKV projection ----------------
// z=0: Q (scaled by beta*log2e so attention uses raw v_exp_f32; [h][seq][64])
// z=1: K ([h][seq][64])
// z=2: V written TRANSPOSED directly: Vt[h][d][seq] (b64 packed stores).
__global__ __launch_bounds__(256, 2) void qkv_gemm_kernel(
        const bf16* __restrict__ xb,
        const bf16* __restrict__ Wqt, const bf16* __restrict__ Wkt, const bf16* __restrict__ Wvt,
        bf16* __restrict__ Qh, bf16* __restrict__ Kh, bf16* __restrict__ Vt) {
    const bf16* Bt;
    if (blockIdx.z == 0)      Bt = Wqt;
    else if (blockIdx.z == 1) Bt = Wkt;
    else                      Bt = Wvt;
    int n0 = blockIdx.x * 128, m0 = blockIdx.y * 128;
    floatx4 acc[4][4];
    gemm128_dbuf(xb, Bt, m0, n0, acc);

    const int tid = threadIdx.x, wave = tid >> 6, lane = tid & 63;
    const int l15 = lane & 15, quad = lane >> 4;
    const int wm = (wave >> 1) * 64, wn = (wave & 1) * 64;
    if (blockIdx.z == 2) {
        #pragma unroll
        for (int i = 0; i < 4; i++)
            #pragma unroll
            for (int j = 0; j < 4; j++) {
                int col = n0 + wn + j * 16 + l15;
                int h = col >> 6, d = col & 63;
                int row0 = m0 + wm + i * 16 + quad * 4;
                uint2 v = pack4bf(acc[i][j][0], acc[i][j][1], acc[i][j][2], acc[i][j][3]);
                *reinterpret_cast<uint2*>(Vt + ((size_t)h * DHEAD + d) * SEQ + row0) = v;
            }
    } else {
        bf16* O = (blockIdx.z == 0) ? Qh : Kh;
        float scale = (blockIdx.z == 0) ? 0.125f * 1.4426950408889634f : 1.0f;
        #pragma unroll
        for (int i = 0; i < 4; i++)
            #pragma unroll
            for (int j = 0; j < 4; j++) {
                int col = n0 + wn + j * 16 + l15;
                int h = col >> 6, d = col & 63;
                #pragma unroll
                for (int r = 0; r < 4; r++) {
                    int row = m0 + wm + i * 16 + quad * 4 + r;
                    O[((size_t)h * SEQ + row) * DHEAD + d] = __float2bfloat16(acc[i][j][r] * scale);
                }
            }
    }
}

// ---------------- output projection: out = Oa @ Wo + bo (fp32 out) ----------------
__global__ __launch_bounds__(256, 2) void out_gemm_kernel(
        const bf16* __restrict__ Oa, const bf16* __restrict__ Wot,
        const float* __restrict__ bo, float* __restrict__ out) {
    int n0 = blockIdx.x * 128, m0 = blockIdx.y * 128;
    floatx4 acc[4][4];
    gemm128_dbuf(Oa, Wot, m0, n0, acc);

    const int tid = threadIdx.x, wave = tid >> 6, lane = tid & 63;
    const int l15 = lane & 15, quad = lane >> 4;
    const int wm = (wave >> 1) * 64, wn = (wave & 1) * 64;
    #pragma unroll
    for (int i = 0; i < 4; i++)
        #pragma unroll
        for (int j = 0; j < 4; j++) {
            int col = n0 + wn + j * 16 + l15;
            float b = bo[col];
            #pragma unroll
            for (int r = 0; r < 4; r++) {
                int row = m0 + wm + i * 16 + quad * 4 + r;
                out[(size_t)row * DIM + col] = acc[i][j][r] + b;
            }
        }
}

// ---------------- causal flash attention (R14: balanced trios over R13 core — WINNER, unchanged) ----------------
// R14 PM: balanced trio map (each CU trio sums 66 tile-units) -> attention left
// the top-5 (<66 µs, was 76.5). Core: mfma_f32_32x32x16_bf16, 4 waves x 32 q,
// BK=64 dbuf, 1 barrier/tile, LDS 32 KB, in-register P via cvt_pk +
// v_permlane32_swap_b32 (T12), split-key additive partials + combine.
// p = v_exp_f32(s) via __builtin_amdgcn_exp2f — do NOT use exp2f (libcall,
// +15 µs R8). DO NOT: drop staging (R6), occupancy <4 blk/CU (R10),
// per-wave K/V-quarter split (R12), unbalanced piece maps (R13).
#define PV_STEP(P, KTG)                                                              \
    do {                                                                             \
        const int rb_ = ((KTG) & 1) * 8;                                             \
        unsigned A0_ = pkbf((P)[rb_ + 0], (P)[rb_ + 1]);                             \
        unsigned B0_ = pkbf((P)[rb_ + 4], (P)[rb_ + 5]);                             \
        unsigned A1_ = pkbf((P)[rb_ + 2], (P)[rb_ + 3]);                             \
        unsigned B1_ = pkbf((P)[rb_ + 6], (P)[rb_ + 7]);                             \
        asm("v_permlane32_swap_b32 %0, %1" : "+v"(A0_), "+v"(B0_));                  \
        asm("v_permlane32_swap_b32 %0, %1" : "+v"(A1_), "+v"(B1_));                  \
        uint4 w_; w_.x = A0_; w_.y = A1_; w_.z = B0_; w_.w = B1_;                    \
        short8 bp_ = *reinterpret_cast<short8*>(&w_);                                \
        short8 av0_ = *reinterpret_cast<const short8*>(                              \
            &Vsh[cur][(KTG) * 512 + lane * 8]);                                      \
        short8 av1_ = *reinterpret_cast<const short8*>(                              \
            &Vsh[cur][(4 + (KTG)) * 512 + lane * 8]);                                \
        acc0 = __builtin_amdgcn_mfma_f32_32x32x16_bf16(av0_, bp_, acc0, 0, 0, 0);    \
        acc1 = __builtin_amdgcn_mfma_f32_32x32x16_bf16(av1_, bp_, acc1, 0, 0, 0);    \
    } while (0)

__global__ __launch_bounds__(256, 4) void attention_kernel(
        const bf16* __restrict__ Qh, const bf16* __restrict__ Kh,
        const bf16* __restrict__ Vt, bf16* __restrict__ Oa,
        float* __restrict__ Op0, float* __restrict__ Op1,
        float* __restrict__ L0, float* __restrict__ L1) {
    __shared__ __align__(16) bf16 Ksh[2][4096];  // 8 KB/buf: chunk t=g*4+kc (keys g*32.., k kc*16..)
    __shared__ __align__(16) bf16 Vsh[2][4096];  // 8 KB/buf: chunk t=dg*4+kt (d dg*32.., key kt*16..)
    const int tid = threadIdx.x, wave = tid >> 6, lane = tid & 63;
    const int ql = lane & 31, half = lane >> 5;
    const int h8 = half * 8;
    const int id = blockIdx.x;
    const int head = id & 15;                    // XCD id&7 serves heads {h, h+8}
    const int rk = id >> 4;                      // 0..47
    // BALANCED piece map: co-resident trio rk {r, r+16, r+32} sums to 66:
    // rk<16:      chunk0 of t=16+rk          (len 32)
    // rk in 16..31: chunk1 of t=47-rk        (len 32-2(rk-16))
    // rk in 32..47: single  t=rk-32          (len 2(rk-32)+2)
    int t, ck;
    if (rk < 16)      { t = 16 + rk; ck = 0; }
    else if (rk < 32) { t = 47 - rk; ck = 1; }
    else              { t = rk - 32; ck = 0; }
    const bool split = (t >= 16);
    const int ktile0 = (split && ck == 1) ? 32 : 0;
    const int ktile1 = (split && ck == 0) ? 32 : (2 * t + 2);
    const int qw = t * 128 + wave * 32;          // wave's 32 q-rows
    const int q = qw + ql;                       // this lane's q-row (n = lane&31)
    const size_t hoff = (size_t)head * SEQ * DHEAD;
    const bf16* Qb = Qh + hoff;
    const bf16* Kb = Kh + hoff;
    const bf16* Vb = Vt + hoff;                  // [d][seq]

    // Q as B-frags for 32x32x16: lane n=q, k = kc*16 + 8*half + j
    short8 bq[4];
    #pragma unroll
    for (int kc = 0; kc < 4; kc++)
        bq[kc] = *reinterpret_cast<const short8*>(
            Qb + (size_t)q * DHEAD + kc * 16 + h8);

    floatx16 acc0, acc1;                         // O: d = (reg&3)+8*(reg>>2)+4*half (+32 for acc1), col q
    #pragma unroll
    for (int r = 0; r < 16; r++) { acc0[r] = 0.f; acc1[r] = 0.f; }
    float l_part = 0.f;

    // per-wave stage of one 64-key K tile + V tile into buffer `buf`
    auto stage = [&](int buf, int kbase) {
        #pragma unroll
        for (int j = 0; j < 2; j++) {
            int tc = wave * 2 + j;               // 0..7 across 4 waves
            gll16(Kb + (size_t)(kbase + (tc >> 2) * 32 + ql) * DHEAD + (tc & 3) * 16 + h8,
                  &Ksh[buf][tc * 512]);
            gll16(Vb + (size_t)((tc >> 2) * 32 + ql) * SEQ + kbase + (tc & 3) * 16 + h8,
                  &Vsh[buf][tc * 512]);
        }
    };

    stage(0, ktile0 * 64);
    __syncthreads();                             // vmcnt(0) drain + first tile visible
    int cur = 0;
    for (int kt = ktile0; kt < ktile1; kt++) {
        const int kbase = kt * 64;
        if (kt + 1 < ktile1) stage(cur ^ 1, (kt + 1) * 64);  // async prefetch

        // S^T = K·Q^T: 8 A-frag reads feed 8 32x32x16 MFMAs (2 key-groups)
        floatx16 s0, s1;
        #pragma unroll
        for (int r = 0; r < 16; r++) { s0[r] = 0.f; s1[r] = 0.f; }
        __builtin_amdgcn_s_setprio(1);
        #pragma unroll
        for (int kc = 0; kc < 4; kc++) {
            short8 ak0 = *reinterpret_cast<const short8*>(&Ksh[cur][kc * 512 + lane * 8]);
            short8 ak1 = *reinterpret_cast<const short8*>(&Ksh[cur][(4 + kc) * 512 + lane * 8]);
            s0 = __builtin_amdgcn_mfma_f32_32x32x16_bf16(ak0, bq[kc], s0, 0, 0, 0);
            s1 = __builtin_amdgcn_mfma_f32_32x32x16_bf16(ak1, bq[kc], s1, 0, 0, 0);
        }
        __builtin_amdgcn_s_setprio(0);
        // causal mask: key = kbase + 32*sg + (r&3)+8*(r>>2)+4*half, q = q
        if (kbase + 63 > qw) {                   // wave-uniform
            int base0 = kbase + half * 4 - q;
            #pragma unroll
            for (int r = 0; r < 16; r++) {
                int off = (r & 3) + 8 * (r >> 2);
                if (base0 + off > 0)      s0[r] = -1e30f;
                if (base0 + 32 + off > 0) s1[r] = -1e30f;
            }
        }
        // p = 2^s in place (masked -> 0); per-lane denom partial
        #pragma unroll
        for (int r = 0; r < 16; r++) {
            s0[r] = __builtin_amdgcn_exp2f(s0[r]);
            s1[r] = __builtin_amdgcn_exp2f(s1[r]);
            l_part += s0[r] + s1[r];
        }
        // O += V^T·P: per 16-key slot build bp in-register (T12) + 2 MFMAs
        __builtin_amdgcn_s_setprio(1);
        PV_STEP(s0, 0); PV_STEP(s0, 1); PV_STEP(s1, 2); PV_STEP(s1, 3);
        __builtin_amdgcn_s_setprio(0);

        __syncthreads();                         // readers done + prefetch drained
        cur ^= 1;
    }
    // denom: lane holds half the keys; other half sits at lane^32
    float l = l_part + __shfl_xor(l_part, 32, 64);
    if (!split) {
        // single-chunk: finalize. Oa row-major [SEQ][INNER].
        float rcp = 1.0f / l;
        #pragma unroll
        for (int a = 0; a < 4; a++) {
            int d0 = 8 * a + half * 4;
            uint2 v0 = pack4bf(acc0[4 * a + 0] * rcp, acc0[4 * a + 1] * rcp,
                               acc0[4 * a + 2] * rcp, acc0[4 * a + 3] * rcp);
            *reinterpret_cast<uint2*>(Oa + (size_t)q * INNER + head * DHEAD + d0) = v0;
            uint2 v1 = pack4bf(acc1[4 * a + 0] * rcp, acc1[4 * a + 1] * rcp,
                               acc1[4 * a + 2] * rcp, acc1[4 * a + 3] * rcp);
            *reinterpret_cast<uint2*>(Oa + (size_t)q * INNER + head * DHEAD + 32 + d0) = v1;
        }
    } else {
        // split: write unnormalized fp32 partials (q in [2048,4096))
        float* Op = ck ? Op1 : Op0;
        float* Lp = ck ? L1 : L0;
        if (half == 0) Lp[head * 2048 + (q - 2048)] = l;
        #pragma unroll
        for (int a = 0; a < 4; a++) {
            int d0 = 8 * a + half * 4;
            floatx4 v0 = {acc0[4 * a + 0], acc0[4 * a + 1], acc0[4 * a + 2], acc0[4 * a + 3]};
            *reinterpret_cast<floatx4*>(
                Op + (size_t)(q - 2048) * INNER + head * DHEAD + d0) = v0;
            floatx4 v1 = {acc1[4 * a + 0], acc1[4 * a + 1], acc1[4 * a + 2], acc1[4 * a + 3]};
            *reinterpret_cast<floatx4*>(
                Op + (size_t)(q - 2048) * INNER + head * DHEAD + 32 + d0) = v1;
        }
    }
}

// ---------------- combine: rows 2048..4095 = (O0+O1)/(l0+l1) -> bf16 Oa ----------------
__global__ __launch_bounds__(256) void combine_kernel(
        const float* __restrict__ Op0, const float* __restrict__ Op1,
        const float* __restrict__ L0, const float* __restrict__ L1,
        bf16* __restrict__ Oa) {
    int idx = blockIdx.x * 256 + threadIdx.x;    // 524288 threads, 4 floats each
    int row = idx >> 8;                          // 0..2047 (q = 2048 + row)
    int c4 = (idx & 255) * 4;                    // col base
    int head = c4 >> 6;
    float l = L0[head * 2048 + row] + L1[head * 2048 + row];
    float rcp = 1.0f / l;
    float4 a = *reinterpret_cast<const float4*>(Op0 + (size_t)row * INNER + c4);
    float4 b = *reinterpret_cast<const float4*>(Op1 + (size_t)row * INNER + c4);
    uint2 v = pack4bf((a.x + b.x) * rcp, (a.y + b.y) * rcp,
                      (a.z + b.z) * rcp, (a.w + b.w) * rcp);
    *reinterpret_cast<uint2*>(Oa + (size_t)(2048 + row) * INNER + c4) = v;
}

extern "C" void kernel_launch(void* const* d_in, const int* in_sizes, int n_in,
                              void* d_out, int out_size, void* d_ws, size_t ws_size,
                              hipStream_t stream) {
    const float* x  = (const float*)d_in[0];
    const float* Wq = (const float*)d_in[1];
    const float* Wk = (const float*)d_in[2];
    const float* Wv = (const float*)d_in[3];
    const float* Wo = (const float*)d_in[4];
    const float* bo = (const float*)d_in[5];
    float* out = (float*)d_out;

    char* ws = (char*)d_ws;
    size_t off = 0;
    bf16* xb  = (bf16*)(ws + off); off += (size_t)SEQ * DIM * 2;
    bf16* Wqt = (bf16*)(ws + off); off += (size_t)DIM * INNER * 2;
    bf16* Wkt = (bf16*)(ws + off); off += (size_t)DIM * INNER * 2;
    bf16* Wvt = (bf16*)(ws + off); off += (size_t)DIM * INNER * 2;
    bf16* Wot = (bf16*)(ws + off); off += (size_t)INNER * DIM * 2;
    bf16* Qh  = (bf16*)(ws + off); off += (size_t)NHEADS * SEQ * DHEAD * 2;
    bf16* Kh  = (bf16*)(ws + off); off += (size_t)NHEADS * SEQ * DHEAD * 2;
    bf16* Vtr = (bf16*)(ws + off); off += (size_t)NHEADS * DHEAD * SEQ * 2;
    bf16* Oa  = (bf16*)(ws + off); off += (size_t)SEQ * INNER * 2;
    float* Op0 = (float*)(ws + off); off += (size_t)(SEQ / 2) * INNER * 4;  // 8 MB
    float* Op1 = (float*)(ws + off); off += (size_t)(SEQ / 2) * INNER * 4;  // 8 MB
    float* L0  = (float*)(ws + off); off += (size_t)NHEADS * (SEQ / 2) * 4;
    float* L1  = (float*)(ws + off); off += (size_t)NHEADS * (SEQ / 2) * 4;  // ~64.5 MB total

    prep_kernel<<<dim3(32, 32, 5), dim3(32, 8), 0, stream>>>(x, Wq, Wk, Wv, Wo,
                                                             xb, Wqt, Wkt, Wvt, Wot);
    qkv_gemm_kernel<<<dim3(8, 32, 3), 256, 0, stream>>>(xb, Wqt, Wkt, Wvt, Qh, Kh, Vtr);
    attention_kernel<<<768, 256, 0, stream>>>(Qh, Kh, Vtr, Oa, Op0, Op1, L0, L1);
    combine_kernel<<<2048, 256, 0, stream>>>(Op0, Op1, L0, L1, Oa);
    out_gemm_kernel<<<dim3(8, 32), 256, 0, stream>>>(Oa, Wot, bo, out);
}

// Round 10
// 225.513 us; speedup vs baseline: 1.2288x; 1.0503x over previous
//
#include <hip/hip_runtime.h>
#include <hip/hip_bf16.h>
#include <stdint.h>
#include <math.h>

#define SEQ 4096
#define DIM 1024
#define NHEADS 16
#define DHEAD 64
#define INNER 1024

typedef __hip_bfloat16 bf16;
typedef __attribute__((ext_vector_type(8))) short short8;
typedef __attribute__((ext_vector_type(4))) float floatx4;
typedef __attribute__((ext_vector_type(16))) float floatx16;

// async global->LDS, 16B per lane; lane i's 16B lands at dest + i*16.
__device__ __forceinline__ void gll16(const bf16* g, bf16* l) {
    __builtin_amdgcn_global_load_lds(
        (const __attribute__((address_space(1))) unsigned int*)g,
        (__attribute__((address_space(3))) unsigned int*)l,
        16, 0, 0);
}

__device__ __forceinline__ unsigned short f2bf_bits(float f) {
    bf16 h = __float2bfloat16(f);
    return *reinterpret_cast<unsigned short*>(&h);
}

__device__ __forceinline__ uint2 pack4bf(float a, float b, float c, float d) {
    __hip_bfloat162 lo = __float22bfloat162_rn(float2{a, b});
    __hip_bfloat162 hi = __float22bfloat162_rn(float2{c, d});
    uint2 r;
    r.x = *reinterpret_cast<unsigned*>(&lo);
    r.y = *reinterpret_cast<unsigned*>(&hi);
    return r;
}

// pack two f32 -> one dword of 2 bf16 (lo in [15:0], hi in [31:16]), RNE
__device__ __forceinline__ unsigned pkbf(float lo, float hi) {
    __hip_bfloat162 h = __float22bfloat162_rn(float2{lo, hi});
    return *reinterpret_cast<unsigned*>(&h);
}

// ---------------- prep: z=0..3 weight transpose+convert; z=4 x convert ----------------
__global__ __launch_bounds__(256) void prep_kernel(
        const float* __restrict__ x, const float* __restrict__ W0,
        const float* __restrict__ W1, const float* __restrict__ W2,
        const float* __restrict__ W3, bf16* __restrict__ xb,
        bf16* __restrict__ T0, bf16* __restrict__ T1,
        bf16* __restrict__ T2, bf16* __restrict__ T3) {
    const int tid = threadIdx.x + threadIdx.y * blockDim.x;  // 0..255
    if (blockIdx.z == 4) {
        // convert x: block (bx,by) -> chunk (by*32+bx) of 4096 floats
        int chunk = blockIdx.y * 32 + blockIdx.x;
        int base = chunk * 4096 + tid * 4;
        #pragma unroll
        for (int r = 0; r < 4; r++) {
            int i = base + r * 1024;
            float4 f = *reinterpret_cast<const float4*>(x + i);
            unsigned long long p = (unsigned long long)f2bf_bits(f.x)
                                 | ((unsigned long long)f2bf_bits(f.y) << 16)
                                 | ((unsigned long long)f2bf_bits(f.z) << 32)
                                 | ((unsigned long long)f2bf_bits(f.w) << 48);
            *reinterpret_cast<unsigned long long*>(xb + i) = p;
        }
        return;
    }
    const float* W; bf16* T;
    switch (blockIdx.z) {
        case 0:  W = W0; T = T0; break;
        case 1:  W = W1; T = T1; break;
        case 2:  W = W2; T = T2; break;
        default: W = W3; T = T3; break;
    }
    __shared__ float tile[32][33];
    int k0 = blockIdx.x * 32, n0 = blockIdx.y * 32;
    int tx = threadIdx.x, ty = threadIdx.y;
    #pragma unroll
    for (int i = 0; i < 4; i++)
        tile[ty + 8 * i][tx] = W[(size_t)(k0 + ty + 8 * i) * 1024 + n0 + tx];
    __syncthreads();
    #pragma unroll
    for (int i = 0; i < 4; i++)
        T[(size_t)(n0 + ty + 8 * i) * 1024 + k0 + tx] = __float2bfloat16(tile[tx][ty + 8 * i]);
}

// ---------------- 128x128 bf16 MFMA GEMM tile body, 2-PHASE DOUBLE-BUFFERED ----------------
// (kept for out_gemm: 256 blocks = 1/CU, 2-blk/CU capacity; R17-verified)
__device__ __forceinline__ void gemm128_dbuf(const bf16* __restrict__ A,
                                             const bf16* __restrict__ Bt,
                                             int m0, int n0, floatx4 acc[4][4]) {
    __shared__ __align__(16) bf16 As[2][8192];
    __shared__ __align__(16) bf16 Bs[2][8192];
    const int tid = threadIdx.x;
    const int wave = tid >> 6;
    const int lane = tid & 63;
    const int l15 = lane & 15;
    const int quad = lane >> 4;

    #pragma unroll
    for (int i = 0; i < 4; i++)
        #pragma unroll
        for (int j = 0; j < 4; j++)
            acc[i][j] = (floatx4){0.f, 0.f, 0.f, 0.f};

    auto stage = [&](int buf, int k0) {
        #pragma unroll
        for (int j = 0; j < 4; j++) {
            int t = wave * 4 + j;
            int row = (t >> 1) * 16 + l15;
            int kb = (t & 1) * 32 + quad * 8;
            gll16(A + (size_t)(m0 + row) * 1024 + k0 + kb, &As[buf][t * 512]);
            gll16(Bt + (size_t)(n0 + row) * 1024 + k0 + kb, &Bs[buf][t * 512]);
        }
    };

    stage(0, 0);
    __syncthreads();                              // vmcnt(0) drain; tile 0 visible
    int cur = 0;
    for (int k0 = 0; k0 < 1024; k0 += 64) {
        if (k0 + 64 < 1024) stage(cur ^ 1, k0 + 64);   // async prefetch next tile
        #pragma unroll
        for (int ks = 0; ks < 2; ks++) {
            short8 af[4], bfr[4];
            #pragma unroll
            for (int i = 0; i < 4; i++)
                af[i] = *reinterpret_cast<const short8*>(
                    &As[cur][((((wave >> 1) * 4 + i) * 2 + ks) * 512) + lane * 8]);
            #pragma unroll
            for (int j = 0; j < 4; j++)
                bfr[j] = *reinterpret_cast<const short8*>(
                    &Bs[cur][((((wave & 1) * 4 + j) * 2 + ks) * 512) + lane * 8]);
            #pragma unroll
            for (int i = 0; i < 4; i++)
                #pragma unroll
                for (int j = 0; j < 4; j++)
                    acc[i][j] = __builtin_amdgcn_mfma_f32_16x16x32_bf16(af[i], bfr[j], acc[i][j], 0, 0, 0);
        }
        __syncthreads();                          // readers done + prefetch drained
        cur ^= 1;
    }
}

// ---------------- QKV projection: 256x256 2-phase dbuf (R18) ----------------
// R18 POST-MORTEM CHAIN: R14 single-buf = 66 µs; R17 dbuf = 67 µs (NEUTRAL,
// = m99/m100 precedent) -> per-step cost is the barrier/drain EVENT (~2.7k cy),
// not hideable load latency. Fix = fewer, fatter steps: 256x256 tile, 512 thr
// (8 waves 2Mx4N, 128x64/wave), BK=64. Grid (4,16,3) = 192 equal blocks ->
// ONE round on 192 CUs, 16 stall events/CU (was 48), 4x MFMA per step.
// Reference: m248v2 2ph 256^2 K=1024 = 666 TF (we measured 390 at 128^2).
// Same chunk/fragment formulas as R17 (32+32 chunks, 8 gll16/wave/step,
// linear conflict-free lane*16B). LDS 128 KB (m194-m201 proven size).
// z=0: Q (scaled by beta*log2e; [h][seq][64]); z=1: K; z=2: V transposed
// Vt[h][d][seq]. DO NOT: drop LDS staging (R16, 98 µs), narrow tiles for
// occupancy (R15, 77 µs).
__global__ __launch_bounds__(512, 2) void qkv_gemm_kernel(
        const bf16* __restrict__ xb,
        const bf16* __restrict__ Wqt, const bf16* __restrict__ Wkt, const bf16* __restrict__ Wvt,
        bf16* __restrict__ Qh, bf16* __restrict__ Kh, bf16* __restrict__ Vt) {
    __shared__ __align__(16) bf16 As[2][16384];   // 32 chunks x 512 bf16 = 32 KB/buf
    __shared__ __align__(16) bf16 Bs[2][16384];
    const bf16* Bt;
    if (blockIdx.z == 0)      Bt = Wqt;
    else if (blockIdx.z == 1) Bt = Wkt;
    else                      Bt = Wvt;
    const int n0 = blockIdx.x * 256, m0 = blockIdx.y * 256;
    const int tid = threadIdx.x;
    const int wave = tid >> 6;                    // 0..7
    const int lane = tid & 63;
    const int l15 = lane & 15, quad = lane >> 4;
    const int wr = wave >> 2;                     // 0..1: row half (128 rows)
    const int wc = wave & 3;                      // 0..3: col quarter (64 cols)

    floatx4 acc[8][4];
    #pragma unroll
    for (int i = 0; i < 8; i++)
        #pragma unroll
        for (int j = 0; j < 4; j++)
            acc[i][j] = (floatx4){0.f, 0.f, 0.f, 0.f};

    // stage one 256x64 A-tile + B-tile: chunk t = rowgrp(t>>1)*16, khalf(t&1)*32
    auto stage = [&](int buf, int k0) {
        #pragma unroll
        for (int j = 0; j < 4; j++) {
            int t = wave * 4 + j;                 // 0..31
            int row = (t >> 1) * 16 + l15;
            int kb = (t & 1) * 32 + quad * 8;
            gll16(xb + (size_t)(m0 + row) * 1024 + k0 + kb, &As[buf][t * 512]);
            gll16(Bt + (size_t)(n0 + row) * 1024 + k0 + kb, &Bs[buf][t * 512]);
        }
    };

    stage(0, 0);
    __syncthreads();                              // vmcnt(0) drain; tile 0 visible
    int cur = 0;
    for (int k0 = 0; k0 < 1024; k0 += 64) {
        if (k0 + 64 < 1024) stage(cur ^ 1, k0 + 64);   // async prefetch next tile
        #pragma unroll
        for (int ks = 0; ks < 2; ks++) {
            short8 af[8], bfr[4];
            #pragma unroll
            for (int i = 0; i < 8; i++)           // rows wr*128 + i*16
                af[i] = *reinterpret_cast<const short8*>(
                    &As[cur][(((wr * 8 + i) * 2 + ks) * 512) + lane * 8]);
            #pragma unroll
            for (int j = 0; j < 4; j++)           // cols wc*64 + j*16
                bfr[j] = *reinterpret_cast<const short8*>(
                    &Bs[cur][(((wc * 4 + j) * 2 + ks) * 512) + lane * 8]);
            #pragma unroll
            for (int i = 0; i < 8; i++)
                #pragma unroll
                for (int j = 0; j < 4; j++)
                    acc[i][j] = __builtin_amdgcn_mfma_f32_16x16x32_bf16(af[i], bfr[j], acc[i][j], 0, 0, 0);
        }
        __syncthreads();                          // readers done + prefetch drained
        cur ^= 1;
    }

    const int wm = wr * 128, wn = wc * 64;
    if (blockIdx.z == 2) {
        #pragma unroll
        for (int i = 0; i < 8; i++)
            #pragma unroll
            for (int j = 0; j < 4; j++) {
                int col = n0 + wn + j * 16 + l15;
                int h = col >> 6, d = col & 63;
                int row0 = m0 + wm + i * 16 + quad * 4;
                uint2 v = pack4bf(acc[i][j][0], acc[i][j][1], acc[i][j][2], acc[i][j][3]);
                *reinterpret_cast<uint2*>(Vt + ((size_t)h * DHEAD + d) * SEQ + row0) = v;
            }
    } else {
        bf16* O = (blockIdx.z == 0) ? Qh : Kh;
        float scale = (blockIdx.z == 0) ? 0.125f * 1.4426950408889634f : 1.0f;
        #pragma unroll
        for (int i = 0; i < 8; i++)
            #pragma unroll
            for (int j = 0; j < 4; j++) {
                int col = n0 + wn + j * 16 + l15;
                int h = col >> 6, d = col & 63;
                #pragma unroll
                for (int r = 0; r < 4; r++) {
                    int row = m0 + wm + i * 16 + quad * 4 + r;
                    O[((size_t)h * SEQ + row) * DHEAD + d] = __float2bfloat16(acc[i][j][r] * scale);
                }
            }
    }
}

// ---------------- output projection: out = Oa @ Wo + bo (fp32 out) ----------------
// 128^2 dbuf kept: grid 256 = 1 blk/CU in one round; 256^2 would be 64 blocks
// (25% CU util, net worse by the step-event model).
__global__ __launch_bounds__(256, 2) void out_gemm_kernel(
        const bf16* __restrict__ Oa, const bf16* __restrict__ Wot,
        const float* __restrict__ bo, float* __restrict__ out) {
    int n0 = blockIdx.x * 128, m0 = blockIdx.y * 128;
    floatx4 acc[4][4];
    gemm128_dbuf(Oa, Wot, m0, n0, acc);

    const int tid = threadIdx.x, wave = tid >> 6, lane = tid & 63;
    const int l15 = lane & 15, quad = lane >> 4;
    const int wm = (wave >> 1) * 64, wn = (wave & 1) * 64;
    #pragma unroll
    for (int i = 0; i < 4; i++)
        #pragma unroll
        for (int j = 0; j < 4; j++) {
            int col = n0 + wn + j * 16 + l15;
            float b = bo[col];
            #pragma unroll
            for (int r = 0; r < 4; r++) {
                int row = m0 + wm + i * 16 + quad * 4 + r;
                out[(size_t)row * DIM + col] = acc[i][j][r] + b;
            }
        }
}

// ---------------- causal flash attention (R14: balanced trios over R13 core — WINNER, unchanged) ----------------
// R14 PM: balanced trio map (each CU trio sums 66 tile-units) -> attention left
// the top-5 (<66 µs, was 76.5). Core: mfma_f32_32x32x16_bf16, 4 waves x 32 q,
// BK=64 dbuf, 1 barrier/tile, LDS 32 KB, in-register P via cvt_pk +
// v_permlane32_swap_b32 (T12), split-key additive partials + combine.
// p = v_exp_f32(s) via __builtin_amdgcn_exp2f — do NOT use exp2f (libcall,
// +15 µs R8). DO NOT: drop staging (R6), occupancy <4 blk/CU (R10),
// per-wave K/V-quarter split (R12), unbalanced piece maps (R13).
#define PV_STEP(P, KTG)                                                              \
    do {                                                                             \
        const int rb_ = ((KTG) & 1) * 8;                                             \
        unsigned A0_ = pkbf((P)[rb_ + 0], (P)[rb_ + 1]);                             \
        unsigned B0_ = pkbf((P)[rb_ + 4], (P)[rb_ + 5]);                             \
        unsigned A1_ = pkbf((P)[rb_ + 2], (P)[rb_ + 3]);                             \
        unsigned B1_ = pkbf((P)[rb_ + 6], (P)[rb_ + 7]);                             \
        asm("v_permlane32_swap_b32 %0, %1" : "+v"(A0_), "+v"(B0_));                  \
        asm("v_permlane32_swap_b32 %0, %1" : "+v"(A1_), "+v"(B1_));                  \
        uint4 w_; w_.x = A0_; w_.y = A1_; w_.z = B0_; w_.w = B1_;                    \
        short8 bp_ = *reinterpret_cast<short8*>(&w_);                                \
        short8 av0_ = *reinterpret_cast<const short8*>(                              \
            &Vsh[cur][(KTG) * 512 + lane * 8]);                                      \
        short8 av1_ = *reinterpret_cast<const short8*>(                              \
            &Vsh[cur][(4 + (KTG)) * 512 + lane * 8]);                                \
        acc0 = __builtin_amdgcn_mfma_f32_32x32x16_bf16(av0_, bp_, acc0, 0, 0, 0);    \
        acc1 = __builtin_amdgcn_mfma_f32_32x32x16_bf16(av1_, bp_, acc1, 0, 0, 0);    \
    } while (0)

__global__ __launch_bounds__(256, 4) void attention_kernel(
        const bf16* __restrict__ Qh, const bf16* __restrict__ Kh,
        const bf16* __restrict__ Vt, bf16* __restrict__ Oa,
        float* __restrict__ Op0, float* __restrict__ Op1,
        float* __restrict__ L0, float* __restrict__ L1) {
    __shared__ __align__(16) bf16 Ksh[2][4096];  // 8 KB/buf: chunk t=g*4+kc (keys g*32.., k kc*16..)
    __shared__ __align__(16) bf16 Vsh[2][4096];  // 8 KB/buf: chunk t=dg*4+kt (d dg*32.., key kt*16..)
    const int tid = threadIdx.x, wave = tid >> 6, lane = tid & 63;
    const int ql = lane & 31, half = lane >> 5;
    const int h8 = half * 8;
    const int id = blockIdx.x;
    const int head = id & 15;                    // XCD id&7 serves heads {h, h+8}
    const int rk = id >> 4;                      // 0..47
    // BALANCED piece map: co-resident trio rk {r, r+16, r+32} sums to 66:
    // rk<16:      chunk0 of t=16+rk          (len 32)
    // rk in 16..31: chunk1 of t=47-rk        (len 32-2(rk-16))
    // rk in 32..47: single  t=rk-32          (len 2(rk-32)+2)
    int t, ck;
    if (rk < 16)      { t = 16 + rk; ck = 0; }
    else if (rk < 32) { t = 47 - rk; ck = 1; }
    else              { t = rk - 32; ck = 0; }
    const bool split = (t >= 16);
    const int ktile0 = (split && ck == 1) ? 32 : 0;
    const int ktile1 = (split && ck == 0) ? 32 : (2 * t + 2);
    const int qw = t * 128 + wave * 32;          // wave's 32 q-rows
    const int q = qw + ql;                       // this lane's q-row (n = lane&31)
    const size_t hoff = (size_t)head * SEQ * DHEAD;
    const bf16* Qb = Qh + hoff;
    const bf16* Kb = Kh + hoff;
    const bf16* Vb = Vt + hoff;                  // [d][seq]

    // Q as B-frags for 32x32x16: lane n=q, k = kc*16 + 8*half + j
    short8 bq[4];
    #pragma unroll
    for (int kc = 0; kc < 4; kc++)
        bq[kc] = *reinterpret_cast<const short8*>(
            Qb + (size_t)q * DHEAD + kc * 16 + h8);

    floatx16 acc0, acc1;                         // O: d = (reg&3)+8*(reg>>2)+4*half (+32 for acc1), col q
    #pragma unroll
    for (int r = 0; r < 16; r++) { acc0[r] = 0.f; acc1[r] = 0.f; }
    float l_part = 0.f;

    // per-wave stage of one 64-key K tile + V tile into buffer `buf`
    auto stage = [&](int buf, int kbase) {
        #pragma unroll
        for (int j = 0; j < 2; j++) {
            int tc = wave * 2 + j;               // 0..7 across 4 waves
            gll16(Kb + (size_t)(kbase + (tc >> 2) * 32 + ql) * DHEAD + (tc & 3) * 16 + h8,
                  &Ksh[buf][tc * 512]);
            gll16(Vb + (size_t)((tc >> 2) * 32 + ql) * SEQ + kbase + (tc & 3) * 16 + h8,
                  &Vsh[buf][tc * 512]);
        }
    };

    stage(0, ktile0 * 64);
    __syncthreads();                             // vmcnt(0) drain + first tile visible
    int cur = 0;
    for (int kt = ktile0; kt < ktile1; kt++) {
        const int kbase = kt * 64;
        if (kt + 1 < ktile1) stage(cur ^ 1, (kt + 1) * 64);  // async prefetch

        // S^T = K·Q^T: 8 A-frag reads feed 8 32x32x16 MFMAs (2 key-groups)
        floatx16 s0, s1;
        #pragma unroll
        for (int r = 0; r < 16; r++) { s0[r] = 0.f; s1[r] = 0.f; }
        __builtin_amdgcn_s_setprio(1);
        #pragma unroll
        for (int kc = 0; kc < 4; kc++) {
            short8 ak0 = *reinterpret_cast<const short8*>(&Ksh[cur][kc * 512 + lane * 8]);
            short8 ak1 = *reinterpret_cast<const short8*>(&Ksh[cur][(4 + kc) * 512 + lane * 8]);
            s0 = __builtin_amdgcn_mfma_f32_32x32x16_bf16(ak0, bq[kc], s0, 0, 0, 0);
            s1 = __builtin_amdgcn_mfma_f32_32x32x16_bf16(ak1, bq[kc], s1, 0, 0, 0);
        }
        __builtin_amdgcn_s_setprio(0);
        // causal mask: key = kbase + 32*sg + (r&3)+8*(r>>2)+4*half, q = q
        if (kbase + 63 > qw) {                   // wave-uniform
            int base0 = kbase + half * 4 - q;
            #pragma unroll
            for (int r = 0; r < 16; r++) {
                int off = (r & 3) + 8 * (r >> 2);
                if (base0 + off > 0)      s0[r] = -1e30f;
                if (base0 + 32 + off > 0) s1[r] = -1e30f;
            }
        }
        // p = 2^s in place (masked -> 0); per-lane denom partial
        #pragma unroll
        for (int r = 0; r < 16; r++) {
            s0[r] = __builtin_amdgcn_exp2f(s0[r]);
            s1[r] = __builtin_amdgcn_exp2f(s1[r]);
            l_part += s0[r] + s1[r];
        }
        // O += V^T·P: per 16-key slot build bp in-register (T12) + 2 MFMAs
        __builtin_amdgcn_s_setprio(1);
        PV_STEP(s0, 0); PV_STEP(s0, 1); PV_STEP(s1, 2); PV_STEP(s1, 3);
        __builtin_amdgcn_s_setprio(0);

        __syncthreads();                         // readers done + prefetch drained
        cur ^= 1;
    }
    // denom: lane holds half the keys; other half sits at lane^32
    float l = l_part + __shfl_xor(l_part, 32, 64);
    if (!split) {
        // single-chunk: finalize. Oa row-major [SEQ][INNER].
        float rcp = 1.0f / l;
        #pragma unroll
        for (int a = 0; a < 4; a++) {
            int d0 = 8 * a + half * 4;
            uint2 v0 = pack4bf(acc0[4 * a + 0] * rcp, acc0[4 * a + 1] * rcp,
                               acc0[4 * a + 2] * rcp, acc0[4 * a + 3] * rcp);
            *reinterpret_cast<uint2*>(Oa + (size_t)q * INNER + head * DHEAD + d0) = v0;
            uint2 v1 = pack4bf(acc1[4 * a + 0] * rcp, acc1[4 * a + 1] * rcp,
                               acc1[4 * a + 2] * rcp, acc1[4 * a + 3] * rcp);
            *reinterpret_cast<uint2*>(Oa + (size_t)q * INNER + head * DHEAD + 32 + d0) = v1;
        }
    } else {
        // split: write unnormalized fp32 partials (q in [2048,4096))
        float* Op = ck ? Op1 : Op0;
        float* Lp = ck ? L1 : L0;
        if (half == 0) Lp[head * 2048 + (q - 2048)] = l;
        #pragma unroll
        for (int a = 0; a < 4; a++) {
            int d0 = 8 * a + half * 4;
            floatx4 v0 = {acc0[4 * a + 0], acc0[4 * a + 1], acc0[4 * a + 2], acc0[4 * a + 3]};
            *reinterpret_cast<floatx4*>(
                Op + (size_t)(q - 2048) * INNER + head * DHEAD + d0) = v0;
            floatx4 v1 = {acc1[4 * a + 0], acc1[4 * a + 1], acc1[4 * a + 2], acc1[4 * a + 3]};
            *reinterpret_cast<floatx4*>(
                Op + (size_t)(q - 2048) * INNER + head * DHEAD + 32 + d0) = v1;
        }
    }
}

// ---------------- combine: rows 2048..4095 = (O0+O1)/(l0+l1) -> bf16 Oa ----------------
__global__ __launch_bounds__(256) void combine_kernel(
        const float* __restrict__ Op0, const float* __restrict__ Op1,
        const float* __restrict__ L0, const float* __restrict__ L1,
        bf16* __restrict__ Oa) {
    int idx = blockIdx.x * 256 + threadIdx.x;    // 524288 threads, 4 floats each
    int row = idx >> 8;                          // 0..2047 (q = 2048 + row)
    int c4 = (idx & 255) * 4;                    // col base
    int head = c4 >> 6;
    float l = L0[head * 2048 + row] + L1[head * 2048 + row];
    float rcp = 1.0f / l;
    float4 a = *reinterpret_cast<const float4*>(Op0 + (size_t)row * INNER + c4);
    float4 b = *reinterpret_cast<const float4*>(Op1 + (size_t)row * INNER + c4);
    uint2 v = pack4bf((a.x + b.x) * rcp, (a.y + b.y) * rcp,
                      (a.z + b.z) * rcp, (a.w + b.w) * rcp);
    *reinterpret_cast<uint2*>(Oa + (size_t)(2048 + row) * INNER + c4) = v;
}

extern "C" void kernel_launch(void* const* d_in, const int* in_sizes, int n_in,
                              void* d_out, int out_size, void* d_ws, size_t ws_size,
                              hipStream_t stream) {
    const float* x  = (const float*)d_in[0];
    const float* Wq = (const float*)d_in[1];
    const float* Wk = (const float*)d_in[2];
    const float* Wv = (const float*)d_in[3];
    const float* Wo = (const float*)d_in[4];
    const float* bo = (const float*)d_in[5];
    float* out = (float*)d_out;

    char* ws = (char*)d_ws;
    size_t off = 0;
    bf16* xb  = (bf16*)(ws + off); off += (size_t)SEQ * DIM * 2;
    bf16* Wqt = (bf16*)(ws + off); off += (size_t)DIM * INNER * 2;
    bf16* Wkt = (bf16*)(ws + off); off += (size_t)DIM * INNER * 2;
    bf16* Wvt = (bf16*)(ws + off); off += (size_t)DIM * INNER * 2;
    bf16* Wot = (bf16*)(ws + off); off += (size_t)INNER * DIM * 2;
    bf16* Qh  = (bf16*)(ws + off); off += (size_t)NHEADS * SEQ * DHEAD * 2;
    bf16* Kh  = (bf16*)(ws + off); off += (size_t)NHEADS * SEQ * DHEAD * 2;
    bf16* Vtr = (bf16*)(ws + off); off += (size_t)NHEADS * DHEAD * SEQ * 2;
    bf16* Oa  = (bf16*)(ws + off); off += (size_t)SEQ * INNER * 2;
    float* Op0 = (float*)(ws + off); off += (size_t)(SEQ / 2) * INNER * 4;  // 8 MB
    float* Op1 = (float*)(ws + off); off += (size_t)(SEQ / 2) * INNER * 4;  // 8 MB
    float* L0  = (float*)(ws + off); off += (size_t)NHEADS * (SEQ / 2) * 4;
    float* L1  = (float*)(ws + off); off += (size_t)NHEADS * (SEQ / 2) * 4;  // ~64.5 MB total

    prep_kernel<<<dim3(32, 32, 5), dim3(32, 8), 0, stream>>>(x, Wq, Wk, Wv, Wo,
                                                             xb, Wqt, Wkt, Wvt, Wot);
    qkv_gemm_kernel<<<dim3(4, 16, 3), 512, 0, stream>>>(xb, Wqt, Wkt, Wvt, Qh, Kh, Vtr);
    attention_kernel<<<768, 256, 0, stream>>>(Qh, Kh, Vtr, Oa, Op0, Op1, L0, L1);
    combine_kernel<<<2048, 256, 0, stream>>>(Op0, Op1, L0, L1, Oa);
    out_gemm_kernel<<<dim3(8, 32), 256, 0, stream>>>(Oa, Wot, bo, out);
}